// Round 8
// baseline (654.916 us; speedup 1.0000x reference)
//
#include <hip/hip_runtime.h>
#include <hip/hip_bf16.h>

typedef __bf16 bf16_t;
typedef __bf16 bf16x8 __attribute__((ext_vector_type(8)));
typedef float f32x4 __attribute__((ext_vector_type(4)));

#define B_  4
#define S_  2048
#define H_  16
#define DK_ 128
#define DM_ 2048
#define BS_ (B_ * S_)          // 8192 rows

static __device__ __forceinline__ f32x4 mfma16(bf16x8 a, bf16x8 b, f32x4 c) {
  return __builtin_amdgcn_mfma_f32_16x16x32_bf16(a, b, c, 0, 0, 0);
}

// async global->LDS 16B copy. lds base must be wave-uniform; HW scatters lane*16.
static __device__ __forceinline__ void async_copy16(const bf16_t* g, bf16_t* l) {
  __builtin_amdgcn_global_load_lds(
      (const __attribute__((address_space(1))) void*)g,
      (__attribute__((address_space(3))) void*)l, 16, 0, 0);
}

// raw workgroup barrier WITHOUT the vmcnt(0)/lgkmcnt(0) drain __syncthreads
// emits; "memory" clobber = compiler fence.
#define BARRIER() asm volatile("s_barrier" ::: "memory")

// DPP row_ror (within 16-lane row) on f32 -- cross-lane reduce on the VALU pipe.
template <int CTRL>
static __device__ __forceinline__ float dpp_rorf(float x) {
  return __builtin_bit_cast(float,
      __builtin_amdgcn_update_dpp(0, __builtin_bit_cast(int, x), CTRL, 0xF, 0xF, true));
}
static __device__ __forceinline__ float rowmax16(float r) {
  r = fmaxf(r, dpp_rorf<0x121>(r));
  r = fmaxf(r, dpp_rorf<0x122>(r));
  r = fmaxf(r, dpp_rorf<0x124>(r));
  r = fmaxf(r, dpp_rorf<0x128>(r));
  return r;
}
static __device__ __forceinline__ float rowsum16(float r) {
  r += dpp_rorf<0x121>(r);
  r += dpp_rorf<0x122>(r);
  r += dpp_rorf<0x124>(r);
  r += dpp_rorf<0x128>(r);
  return r;
}

struct ChainOn  { static constexpr bool v = true;  };
struct ChainOff { static constexpr bool v = false; };

// ---------------------------------------------------------------------------
// fp32 -> bf16 elementwise convert (8 elems/thread)
// ---------------------------------------------------------------------------
__global__ __launch_bounds__(256) void cvt_bf16(const float* __restrict__ in,
                                                bf16_t* __restrict__ out, int n8) {
  int i = blockIdx.x * 256 + threadIdx.x;
  if (i < n8) {
    const float4* p = (const float4*)in + (size_t)i * 2;
    float4 f0 = p[0], f1 = p[1];
    bf16x8 r;
    r[0] = (bf16_t)f0.x; r[1] = (bf16_t)f0.y; r[2] = (bf16_t)f0.z; r[3] = (bf16_t)f0.w;
    r[4] = (bf16_t)f1.x; r[5] = (bf16_t)f1.y; r[6] = (bf16_t)f1.z; r[7] = (bf16_t)f1.w;
    ((bf16x8*)out)[i] = r;
  }
}

// ---------------------------------------------------------------------------
// GEMM body: C[M,N] = A[M,K] * B[N,K]^T, 256x256 tile, BK=32, 8 waves (2Mx4N).
// r7 post-mortem: 4-phase/K-tile had 8 barriers per K-tile (256/loop) with
// only 16 MFMA per interval -> sync-density-bound (~630 TF). This version:
// ONE phase per BK=32 K-step, ONE barrier per phase (64/loop), 32 MFMA per
// interval, 4-deep LDS buffering [4][256][32] per operand (128 KiB total),
// stage 3 tiles ahead, counted vmcnt(8) only (never 0 in-loop).
//
// Per-phase: stage T(t+3)->slot (t+3)&3 (4 loads) | 12 ds_read_b128 from
// slot t&3 | setprio(1) 32 MFMA setprio(0) | vmcnt(8) | s_barrier.
// Ledger (4 loads/phase/wave, FIFO): at the wait, outstanding = T(t+1),
// T(t+2), T(t+3) = 12 -> vmcnt(8) drains T(t+1), needed NEXT phase and
// issued 2 phases (~1.4K cyc) earlier (covers HBM ~900 cyc).
// Overwrite safety: stage at t writes slot (t+3)&3 = buffer read at t-1,
// whose ds_reads retired (same-wave lgkmcnt before MFMA) before t-1's end
// barrier; the stage is issued after that barrier. Tail: clamped dup-loads
// into provably-dead slots keep the ledger uniform; final vmcnt(0) before
// the epilogue so no lds-DMA lands after LDS reallocation.
//
// Swizzle (refcheck'd r6/r7): row = 4 chunks of 8 elems; logical chunk q of
// row r stored at physical q ^ s(r), s(r) = (r + (r>>2)) & 3. LDS dest stays
// linear for global_load_lds; SOURCE chunk is inverse-swizzled; ds_read
// applies the XOR (s(r) is lane-only for 16-aligned row bases). Per-16-lane
// beat the b128 reads are 2-way aliased = free (m136).
// vtout: write C per-head-transposed into Vt layout [(b*16+h)*128+d][s].
// ---------------------------------------------------------------------------
template <typename TC>
static __device__ __forceinline__ void gemm_body(
    const bf16_t* __restrict__ A, const bf16_t* __restrict__ B, TC* __restrict__ C,
    bool vtout, int b256, bf16_t (&Ab)[4][8192], bf16_t (&Bb)[4][8192]) {
  const int tid  = threadIdx.x;
  const int wave = tid >> 6;              // 0..7
  const int lane = tid & 63;
  const int quad = lane >> 4;
  const int l16  = lane & 15;
  const int wm   = (wave >> 2) * 128;     // wave's M half
  const int wn   = (wave & 3) * 64;       // wave's N quarter

  // XCD-bijective remap: 256 blocks; each xcd owns a contiguous 4x8 stripe.
  const int xcd = b256 & 7;
  const int idx = b256 >> 3;              // 0..31
  const int bm  = (xcd * 4 + (idx >> 3)) * 256;
  const int bn  = (idx & 7) * 256;
  const int K   = DM_;

  // staging: 2 instructions per operand per phase; instr0 rows 0-127 (4
  // lanes/row), instr1 rows 128-255. Source chunk inverse-swizzled.
  const int r0 = wave * 16 + (lane >> 2);
  const int r1 = r0 + 128;
  const int s0 = (r0 + (r0 >> 2)) & 3;
  const int s1 = (r1 + (r1 >> 2)) & 3;
  const size_t aO0 = (size_t)(bm + r0) * K + ((lane & 3) ^ s0) * 8;
  const size_t aO1 = (size_t)(bm + r1) * K + ((lane & 3) ^ s1) * 8;
  const size_t bO0 = (size_t)(bn + r0) * K + ((lane & 3) ^ s0) * 8;
  const size_t bO1 = (size_t)(bn + r1) * K + ((lane & 3) ^ s1) * 8;
  const int dst0 = wave * 512;            // wave-uniform LDS elem offsets
  const int dst1 = 4096 + wave * 512;

  auto stage = [&](int slot, int kt) __attribute__((always_inline)) {
    const size_t c = (size_t)kt * 32;
    async_copy16(A + aO0 + c, &Ab[slot][dst0]);
    async_copy16(A + aO1 + c, &Ab[slot][dst1]);
    async_copy16(B + bO0 + c, &Bb[slot][dst0]);
    async_copy16(B + bO1 + c, &Bb[slot][dst1]);
  };

  // fragment-read swizzle (lane-only: row bases are 16-aligned, wm/4 and
  // wn/4 are multiples of 4)
  const int sw = (l16 + (l16 >> 2)) & 3;
  const int qs = (quad ^ sw) * 8;

  f32x4 acc[8][4];
#pragma unroll
  for (int i = 0; i < 8; ++i)
#pragma unroll
    for (int j = 0; j < 4; ++j) acc[i][j] = (f32x4){0.f, 0.f, 0.f, 0.f};

  const int NT = K >> 5;                  // 64 K-steps

  // prologue: T0,T1,T2 -> slots 0,1,2 (12 loads/wave); T0 resident.
  stage(0, 0); stage(1, 1); stage(2, 2);
  asm volatile("s_waitcnt vmcnt(8)" ::: "memory");
  BARRIER();

  for (int t = 0; t < NT; ++t) {
    const bf16_t* Abuf = Ab[t & 3];
    const bf16_t* Bbuf = Bb[t & 3];
    const int kt = (t + 3 < NT) ? t + 3 : NT - 1;   // clamped tail dups
    stage((t + 3) & 3, kt);

    bf16x8 af[8], bfr[4];
#pragma unroll
    for (int j = 0; j < 8; ++j)
      af[j] = *(const bf16x8*)(&Abuf[(wm + j * 16 + l16) * 32 + qs]);
#pragma unroll
    for (int n = 0; n < 4; ++n)
      bfr[n] = *(const bf16x8*)(&Bbuf[(wn + n * 16 + l16) * 32 + qs]);

    __builtin_amdgcn_s_setprio(1);
#pragma unroll
    for (int j = 0; j < 8; ++j)
#pragma unroll
      for (int n = 0; n < 4; ++n)
        acc[j][n] = mfma16(af[j], bfr[n], acc[j][n]);
    __builtin_amdgcn_s_setprio(0);

    asm volatile("s_waitcnt vmcnt(8)" ::: "memory");  // T(t+1) resident
    BARRIER();
  }

  // drain remaining lds-DMA before epilogue/endpgm (LDS may be reallocated).
  asm volatile("s_waitcnt vmcnt(0)" ::: "memory");

  // epilogue: C/D layout row = quad*4+v, col = l16 per 16x16 fragment
#pragma unroll
  for (int mt = 0; mt < 8; ++mt)
#pragma unroll
    for (int nt = 0; nt < 4; ++nt)
#pragma unroll
      for (int v = 0; v < 4; ++v) {
        int row = bm + wm + mt * 16 + quad * 4 + v;
        int col = bn + wn + nt * 16 + l16;
        if (vtout) {
          // row = b*S+s, col = h*128+d -> Vt[((b*16+h)*128+d)*S + s]
          size_t o = (size_t)(((row >> 11) * 16 + (col >> 7)) * 128 + (col & 127)) * S_ +
                     (row & 2047);
          C[o] = (TC)acc[mt][nt][v];
        } else {
          C[(size_t)row * DM_ + col] = (TC)acc[mt][nt][v];
        }
      }
}

// fused Q/K/V projection: 768 blocks; seg = bid>>8 picks weight + output.
__global__ __launch_bounds__(512, 2) void qkv_gemm(
    const bf16_t* __restrict__ xb, const bf16_t* __restrict__ wq,
    const bf16_t* __restrict__ wk, const bf16_t* __restrict__ wv,
    bf16_t* __restrict__ Qb, bf16_t* __restrict__ Kb, bf16_t* __restrict__ Vt) {
  __shared__ bf16_t Ab[4][8192];
  __shared__ bf16_t Bb[4][8192];
  const int seg  = (int)blockIdx.x >> 8;
  const int b256 = (int)blockIdx.x & 255;
  const bf16_t* W = (seg == 0) ? wq : (seg == 1) ? wk : wv;
  bf16_t* C       = (seg == 0) ? Qb : (seg == 1) ? Kb : Vt;
  gemm_body<bf16_t>(xb, W, C, seg == 2, b256, Ab, Bb);
}

// output projection: fp32 C.
__global__ __launch_bounds__(512, 2) void out_gemm(
    const bf16_t* __restrict__ Ob, const bf16_t* __restrict__ Wob,
    float* __restrict__ out) {
  __shared__ bf16_t Ab[4][8192];
  __shared__ bf16_t Bb[4][8192];
  gemm_body<float>(Ob, Wob, out, false, (int)blockIdx.x, Ab, Bb);
}

// ---------------------------------------------------------------------------
// Flash attention, dual-chain load-balanced version (measured 153.9 us r5):
//  * One workgroup owns TWO q-blocks {qa=31-p, qc=p}: constant 33 work-units.
//  * Both chains consume the SAME staged K/V tile (shared kf/vf ds_reads).
//  * K/V double-buffered, global_load_lds issued one tile ahead.
//  * XOR-swizzled LDS, inverse-swizzled global sources.
//  * DPP row_ror softmax reductions; Q direct global->reg; defer-max; setprio.
// LDS: Ks 32K + Vs 32K + Ps 16K = 80KB -> 2 blocks/CU.
// Q,K: [b*S+s][h*128+d] bf16.  VT: [(b*16+h)*128+d][s] bf16.  O like Q.
// ---------------------------------------------------------------------------
__global__ __launch_bounds__(256, 2) void attn_kernel(const bf16_t* __restrict__ Q,
                                                      const bf16_t* __restrict__ K,
                                                      const bf16_t* __restrict__ VT,
                                                      bf16_t* __restrict__ O,
                                                      const int* __restrict__ use_mask) {
  __shared__ bf16_t Ks[2 * 64 * 128];   // [buf][k][d], XOR-swizzled
  __shared__ bf16_t Vs[2 * 128 * 64];   // [buf][d][k], XOR-swizzled
  __shared__ bf16_t Ps[2 * 4 * 16 * 64];// [chain][wave][16][64], XOR-swizzled

  const int tid  = threadIdx.x;
  const int wave = tid >> 6;
  const int lane = tid & 63;
  const int quad = lane >> 4;
  const int l16  = lane & 15;

  const int lid  = (int)(blockIdx.y * gridDim.x + blockIdx.x);
  const int xcd  = lid & 7;
  const int t8   = lid >> 3;                 // 0..127
  const int bh   = xcd + ((t8 >> 4) << 3);   // 8 heads per XCD
  const int pair = t8 & 15;
  const int qa   = 31 - pair;                // heavy q-block (17..32 tiles)
  const int qc   = pair;                     // light q-block (1..16 tiles)
  const int b = bh >> 4, h = bh & 15;
  const int maskflag = *use_mask;

  const size_t qbaseA = ((size_t)b * S_ + (size_t)qa * 64) * DM_ + h * DK_;
  const size_t qbaseC = ((size_t)b * S_ + (size_t)qc * 64) * DM_ + h * DK_;

  int skO[4], svO[4];
#pragma unroll
  for (int p = 0; p < 4; ++p) {
    int rK = p * 16 + wave * 4 + quad;
    skO[p] = rK * DM_ + ((l16 ^ (rK & 7)) * 8);
    int dV = p * 32 + wave * 8 + (lane >> 3);
    svO[p] = dV * S_ + (((lane & 7) ^ (dV & 7)) * 8);
  }

  const bf16_t* Kbase = K + (size_t)b * S_ * DM_ + h * DK_;
  const bf16_t* Vbase = VT + (size_t)bh * DK_ * S_;

  auto stage_kv = [&](int j, int buf) __attribute__((always_inline)) {
    const bf16_t* kb = Kbase + (size_t)j * 64 * DM_;
    const bf16_t* vb = Vbase + (size_t)j * 64;
    bf16_t* kl = Ks + buf * 8192 + wave * 512;
    bf16_t* vl = Vs + buf * 8192 + wave * 512;
#pragma unroll
    for (int p = 0; p < 4; ++p) {
      async_copy16(kb + skO[p], kl + p * 2048);
      async_copy16(vb + svO[p], vl + p * 2048);
    }
  };

  bf16x8 qfA[4], qfC[4];
#pragma unroll
  for (int kk = 0; kk < 4; ++kk) {
    size_t ro = (size_t)(wave * 16 + l16) * DM_ + kk * 32 + quad * 8;
    qfA[kk] = *(const bf16x8*)(Q + qbaseA + ro);
    qfC[kk] = *(const bf16x8*)(Q + qbaseC + ro);
  }

  stage_kv(0, 0);

  f32x4 accA[8], accC[8];
#pragma unroll
  for (int i = 0; i < 8; ++i) {
    accA[i] = (f32x4){0.f, 0.f, 0.f, 0.f};
    accC[i] = (f32x4){0.f, 0.f, 0.f, 0.f};
  }
  float mA[4], lA[4], mC[4], lC[4];
#pragma unroll
  for (int v = 0; v < 4; ++v) {
    mA[v] = -INFINITY; lA[v] = 0.f;
    mC[v] = -INFINITY; lC[v] = 0.f;
  }

  bf16_t* PwA = Ps + wave * 1024;
  bf16_t* PwC = Ps + 4096 + wave * 1024;

  const float c1 = 0.08838834764831845f * 1.4426950408889634f;

  const int ntA = maskflag ? qa + 1 : (S_ / 64);
  const int ntC = maskflag ? qc + 1 : (S_ / 64);

  auto softmax_chain = [&](f32x4 (&s)[4], float (&mrow)[4], float (&lrow)[4],
                           f32x4 (&acc)[8], bf16_t* Pw, bool masked)
      __attribute__((always_inline)) {
#pragma unroll
    for (int v = 0; v < 4; ++v) {
      float x[4];
#pragma unroll
      for (int nt = 0; nt < 4; ++nt) {
        float y = s[nt][v] * c1;
        if (masked) {
          int kg = nt * 16 + l16;
          int qg = wave * 16 + quad * 4 + v;
          if (kg > qg) y = -INFINITY;
        }
        x[nt] = y;
      }
      float r = fmaxf(fmaxf(x[0], x[1]), fmaxf(x[2], x[3]));
      r = rowmax16(r);
      float m = mrow[v];
      if (r > m + 8.f) {
        float alpha = __builtin_amdgcn_exp2f(m - r);
        lrow[v] *= alpha;
#pragma unroll
        for (int dt = 0; dt < 8; ++dt) acc[dt][v] *= alpha;
        mrow[v] = r;
        m = r;
      }
      float rs = 0.f;
      int prow = quad * 4 + v;
#pragma unroll
      for (int nt = 0; nt < 4; ++nt) {
        float p = __builtin_amdgcn_exp2f(x[nt] - m);
        rs += p;
        Pw[prow * 64 + ((nt * 16 + l16) ^ ((prow & 7) << 3))] = (bf16_t)p;
      }
      lrow[v] += rowsum16(rs);
    }
  };

  auto body = [&](auto DOC, int cur, bool maskedA, bool maskedC)
      __attribute__((always_inline)) {
    constexpr bool doC = decltype(DOC)::v;
    const bf16_t* KsB = Ks + cur * 8192;
    const bf16_t* VsB = Vs + cur * 8192;

    f32x4 sA[4], sC[4];
#pragma unroll
    for (int nt = 0; nt < 4; ++nt) {
      sA[nt] = (f32x4){0.f, 0.f, 0.f, 0.f};
      sC[nt] = (f32x4){0.f, 0.f, 0.f, 0.f};
    }
    __builtin_amdgcn_s_setprio(1);
#pragma unroll
    for (int kk = 0; kk < 4; ++kk) {
#pragma unroll
      for (int nt = 0; nt < 4; ++nt) {
        bf16x8 kf = *(const bf16x8*)(KsB + (nt * 16 + l16) * 128 +
                                     ((kk * 32 + quad * 8) ^ ((l16 & 7) << 3)));
        sA[nt] = mfma16(qfA[kk], kf, sA[nt]);
        if constexpr (doC) sC[nt] = mfma16(qfC[kk], kf, sC[nt]);
      }
    }
    __builtin_amdgcn_s_setprio(0);

    softmax_chain(sA, mA, lA, accA, PwA, maskedA);
    if constexpr (doC) softmax_chain(sC, mC, lC, accC, PwC, maskedC);

    __builtin_amdgcn_s_setprio(1);
#pragma unroll
    for (int kk = 0; kk < 2; ++kk) {
      bf16x8 pfA = *(const bf16x8*)(PwA + l16 * 64 +
                                    ((kk * 32 + quad * 8) ^ ((l16 & 7) << 3)));
      bf16x8 pfC = {};
      if constexpr (doC)
        pfC = *(const bf16x8*)(PwC + l16 * 64 +
                               ((kk * 32 + quad * 8) ^ ((l16 & 7) << 3)));
#pragma unroll
      for (int dt = 0; dt < 8; ++dt) {
        bf16x8 vf = *(const bf16x8*)(VsB + (dt * 16 + l16) * 64 +
                                     ((kk * 32 + quad * 8) ^ ((l16 & 7) << 3)));
        accA[dt] = mfma16(pfA, vf, accA[dt]);
        if constexpr (doC) accC[dt] = mfma16(pfC, vf, accC[dt]);
      }
    }
    __builtin_amdgcn_s_setprio(0);
  };

  __syncthreads();

  for (int t = 0; t < ntA; ++t) {
    const int cur = t & 1;
    if (t + 1 < ntA) stage_kv(t + 1, cur ^ 1);
    const bool mAf = maskflag && (t == qa);
    if (t < ntC)
      body(ChainOn{},  cur, mAf, maskflag && (t == qc));
    else
      body(ChainOff{}, cur, mAf, false);
    __syncthreads();
  }

  auto epilogue = [&](f32x4 (&acc)[8], float (&lrow)[4], size_t qbase)
      __attribute__((always_inline)) {
    float rl[4];
#pragma unroll
    for (int v = 0; v < 4; ++v) rl[v] = __builtin_amdgcn_rcpf(lrow[v]);
#pragma unroll
    for (int dt = 0; dt < 8; ++dt)
#pragma unroll
      for (int v = 0; v < 4; ++v) {
        int qr = wave * 16 + quad * 4 + v;
        O[qbase + (size_t)qr * DM_ + dt * 16 + l16] = (bf16_t)(acc[dt][v] * rl[v]);
      }
  };
  epilogue(accA, lA, qbaseA);
  epilogue(accC, lC, qbaseC);
}

// ---------------------------------------------------------------------------
extern "C" void kernel_launch(void* const* d_in, const int* in_sizes, int n_in,
                              void* d_out, int out_size, void* d_ws, size_t ws_size,
                              hipStream_t stream) {
  const float* x  = (const float*)d_in[0];
  const float* Wq = (const float*)d_in[1];
  const float* Wk = (const float*)d_in[2];
  const float* Wv = (const float*)d_in[3];
  const float* Wo = (const float*)d_in[4];
  const int* use_mask = (const int*)d_in[5];
  float* out = (float*)d_out;

  const size_t TSZ = (size_t)BS_ * DM_;   // 16,777,216 elems (32 MiB bf16)
  const size_t WSZ = (size_t)DM_ * DM_;   //  4,194,304 elems ( 8 MiB bf16)
  bf16_t* Qb  = (bf16_t*)d_ws;            // R0
  bf16_t* Kb  = Qb + TSZ;                 // R1
  bf16_t* Vt  = Kb + TSZ;                 // R2: Vt, then Wo_bf16 after attention
  bf16_t* xb  = Vt + TSZ;                 // R3: x_bf16, then Ob after projections
  bf16_t* Ob  = xb;
  bf16_t* Wob = Vt;
  // weight bf16 staging inside d_out (64 MiB fp32; fully overwritten at the end)
  bf16_t* wq = (bf16_t*)d_out;
  bf16_t* wk = wq + WSZ;
  bf16_t* wv = wk + WSZ;

  cvt_bf16<<<(int)(TSZ / 8 / 256), 256, 0, stream>>>(x,  xb, (int)(TSZ / 8));
  cvt_bf16<<<(int)(WSZ / 8 / 256), 256, 0, stream>>>(Wq, wq, (int)(WSZ / 8));
  cvt_bf16<<<(int)(WSZ / 8 / 256), 256, 0, stream>>>(Wk, wk, (int)(WSZ / 8));
  cvt_bf16<<<(int)(WSZ / 8 / 256), 256, 0, stream>>>(Wv, wv, (int)(WSZ / 8));

  qkv_gemm<<<dim3(768), 512, 0, stream>>>(xb, wq, wk, wv, Qb, Kb, Vt);

  dim3 gA(16, 64);                   // 1024 balanced dual-q blocks
  attn_kernel<<<gA, 256, 0, stream>>>(Qb, Kb, Vt, Ob, use_mask);

  cvt_bf16<<<(int)(WSZ / 8 / 256), 256, 0, stream>>>(Wo, Wob, (int)(WSZ / 8));
  out_gemm<<<dim3(256), 512, 0, stream>>>(Ob, Wob, out);
}

// Round 9
// 601.234 us; speedup vs baseline: 1.0893x; 1.0893x over previous
//
#include <hip/hip_runtime.h>
#include <hip/hip_bf16.h>

typedef __bf16 bf16_t;
typedef __bf16 bf16x8 __attribute__((ext_vector_type(8)));
typedef float f32x4 __attribute__((ext_vector_type(4)));

#define B_  4
#define S_  2048
#define H_  16
#define DK_ 128
#define DM_ 2048
#define BS_ (B_ * S_)          // 8192 rows

static __device__ __forceinline__ f32x4 mfma16(bf16x8 a, bf16x8 b, f32x4 c) {
  return __builtin_amdgcn_mfma_f32_16x16x32_bf16(a, b, c, 0, 0, 0);
}

// async global->LDS 16B copy. lds base must be wave-uniform; HW scatters lane*16.
static __device__ __forceinline__ void async_copy16(const bf16_t* g, bf16_t* l) {
  __builtin_amdgcn_global_load_lds(
      (const __attribute__((address_space(1))) void*)g,
      (__attribute__((address_space(3))) void*)l, 16, 0, 0);
}

// raw workgroup barrier WITHOUT the vmcnt(0)/lgkmcnt(0) drain __syncthreads
// emits; "memory" clobber = compiler fence.
#define BARRIER() asm volatile("s_barrier" ::: "memory")
#define WAIT_VM6() asm volatile("s_waitcnt vmcnt(6)" ::: "memory")

// DPP row_ror (within 16-lane row) on f32 -- cross-lane reduce on the VALU pipe.
template <int CTRL>
static __device__ __forceinline__ float dpp_rorf(float x) {
  return __builtin_bit_cast(float,
      __builtin_amdgcn_update_dpp(0, __builtin_bit_cast(int, x), CTRL, 0xF, 0xF, true));
}
static __device__ __forceinline__ float rowmax16(float r) {
  r = fmaxf(r, dpp_rorf<0x121>(r));
  r = fmaxf(r, dpp_rorf<0x122>(r));
  r = fmaxf(r, dpp_rorf<0x124>(r));
  r = fmaxf(r, dpp_rorf<0x128>(r));
  return r;
}
static __device__ __forceinline__ float rowsum16(float r) {
  r += dpp_rorf<0x121>(r);
  r += dpp_rorf<0x122>(r);
  r += dpp_rorf<0x124>(r);
  r += dpp_rorf<0x128>(r);
  return r;
}

struct ChainOn  { static constexpr bool v = true;  };
struct ChainOff { static constexpr bool v = false; };

// ---------------------------------------------------------------------------
// fp32 -> bf16 elementwise convert (8 elems/thread)
// ---------------------------------------------------------------------------
__global__ __launch_bounds__(256) void cvt_bf16(const float* __restrict__ in,
                                                bf16_t* __restrict__ out, int n8) {
  int i = blockIdx.x * 256 + threadIdx.x;
  if (i < n8) {
    const float4* p = (const float4*)in + (size_t)i * 2;
    float4 f0 = p[0], f1 = p[1];
    bf16x8 r;
    r[0] = (bf16_t)f0.x; r[1] = (bf16_t)f0.y; r[2] = (bf16_t)f0.z; r[3] = (bf16_t)f0.w;
    r[4] = (bf16_t)f1.x; r[5] = (bf16_t)f1.y; r[6] = (bf16_t)f1.z; r[7] = (bf16_t)f1.w;
    ((bf16x8*)out)[i] = r;
  }
}

// ---------------------------------------------------------------------------
// GEMM body: C[M,N] = A[M,K] * B[N,K]^T, 256x256 tile, 8 waves (2Mx4N).
// r8 post-mortem: ring-4/stage-ahead-3 waits EVERY phase on a tile with only
// ~2.3-phase (~700cyc) flight < HBM latency -> convoy at 1 block/CU.
// This version = m201 8-phase schedule, ledger-derived:
//   iter I covers K-tiles e=2I (buf0), o=2I+1 (buf1), BK=64, kh = 32-col half.
//   Phase p: [wait vmcnt(6) if p in {1,5}] [s_barrier] [ds_read quadrant
//   frags] [stage ONE half-tile = 2 loads/thread] [setprio1, 16 MFMA, setprio0]
//   Reads:  p1:A0kh0/mh0+B0kh0  p2:A0kh0/mh1  p3:A0kh1/mh0+B0kh1  p4:A0kh1/mh1
//           p5:A1kh0/mh0+B1kh0  p6:A1kh0/mh1  p7:A1kh1/mh0+B1kh1  p8:A1kh1/mh1
//   Stages: p1:A[b1]kh1<-o   p2:B[b0]kh0<-e+2  p3:A[b0]kh0<-e+2  p4:B[b0]kh1<-e+2
//           p5:A[b0]kh1<-e+2 p6:B[b1]kh0<-o+2  p7:A[b1]kh0<-o+2  p8:B[b1]kh1<-o+2
//   Ledger (2 loads/stage, FIFO): at p1-wait outstanding = {p6,p7,p8 of I-1}
//   = 6 -> completed through I-1.p5 = all p1+p3 needs. At p5-wait outstanding
//   = {I.p2,p3,p4} = 6 -> completed through I.p1 = all p5+p7 needs. Every
//   half flies 6-7 phases (~1200+ cyc) before its wait -> covers HBM ~900.
//   Overwrite safety: stage at p targets the half whose last ds_reads retired
//   before the barrier at p's start (1-phase gap minimum, checked per-entry).
//   Prologue: stage 7 halves {B0kh0,A0kh0,B0kh1,A0kh1,B1kh0,A1kh0,B1kh1} of
//   tiles 0,1 -> first p1-wait lands in steady state. Tail stages clamp to
//   tile NT-1 (written into halves never read). Final vmcnt(0) before the
//   epilogue so no lds-DMA lands after LDS reallocation.
// Swizzle (refcheck'd r6-r8): row = 4 chunks of 8 elems; chunk q of row r at
// physical q ^ s(r), s(r) = (r + (r>>2)) & 3. LDS dest linear for
// global_load_lds; SOURCE chunk inverse-swizzled; ds_read applies the XOR.
// vtout: write C per-head-transposed into Vt layout [(b*16+h)*128+d][s].
// ---------------------------------------------------------------------------
template <typename TC>
static __device__ __forceinline__ void gemm_body(
    const bf16_t* __restrict__ A, const bf16_t* __restrict__ B, TC* __restrict__ C,
    bool vtout, int b256, bf16_t (&Ab)[2][2][8192], bf16_t (&Bb)[2][2][8192]) {
  const int tid  = threadIdx.x;
  const int wave = tid >> 6;              // 0..7
  const int lane = tid & 63;
  const int quad = lane >> 4;
  const int l16  = lane & 15;
  const int wm   = (wave >> 2) * 128;     // wave's M half
  const int wn   = (wave & 3) * 64;       // wave's N quarter

  // XCD-bijective remap: 256 blocks; each xcd owns a contiguous 4x8 stripe.
  const int xcd = b256 & 7;
  const int idx = b256 >> 3;              // 0..31
  const int bm  = (xcd * 4 + (idx >> 3)) * 256;
  const int bn  = (idx & 7) * 256;
  const int K   = DM_;

  // staging: one half-tile (256 rows x 32 cols) = 2 instructions/thread.
  // instr0 rows 0-127 (wave w -> rows w*16..+16, 4 lanes/row), instr1 +128.
  const int r0 = wave * 16 + (lane >> 2);
  const int r1 = r0 + 128;
  const int s0 = (r0 + (r0 >> 2)) & 3;
  const int s1 = (r1 + (r1 >> 2)) & 3;
  const size_t aO0 = (size_t)(bm + r0) * K + ((lane & 3) ^ s0) * 8;
  const size_t aO1 = (size_t)(bm + r1) * K + ((lane & 3) ^ s1) * 8;
  const size_t bO0 = (size_t)(bn + r0) * K + ((lane & 3) ^ s0) * 8;
  const size_t bO1 = (size_t)(bn + r1) * K + ((lane & 3) ^ s1) * 8;
  const int dst0 = wave * 512;            // wave-uniform LDS elem offsets
  const int dst1 = 4096 + wave * 512;

  auto stA = [&](int buf, int kh, int kt) __attribute__((always_inline)) {
    const size_t c = (size_t)kt * 64 + kh * 32;
    async_copy16(A + aO0 + c, &Ab[buf][kh][dst0]);
    async_copy16(A + aO1 + c, &Ab[buf][kh][dst1]);
  };
  auto stB = [&](int buf, int kh, int kt) __attribute__((always_inline)) {
    const size_t c = (size_t)kt * 64 + kh * 32;
    async_copy16(B + bO0 + c, &Bb[buf][kh][dst0]);
    async_copy16(B + bO1 + c, &Bb[buf][kh][dst1]);
  };

  // fragment-read swizzle (lane-only: row bases are 16-aligned)
  const int sw = (l16 + (l16 >> 2)) & 3;
  const int qs = (quad ^ sw) * 8;

  f32x4 acc[8][4];
#pragma unroll
  for (int i = 0; i < 8; ++i)
#pragma unroll
    for (int j = 0; j < 4; ++j) acc[i][j] = (f32x4){0.f, 0.f, 0.f, 0.f};

  bf16x8 af[4], bfr[4];

  auto lda = [&](int buf, int kh, int mh) __attribute__((always_inline)) {
#pragma unroll
    for (int i = 0; i < 4; ++i)
      af[i] = *(const bf16x8*)(&Ab[buf][kh][(wm + mh * 64 + i * 16 + l16) * 32 + qs]);
  };
  auto ldb = [&](int buf, int kh) __attribute__((always_inline)) {
#pragma unroll
    for (int n = 0; n < 4; ++n)
      bfr[n] = *(const bf16x8*)(&Bb[buf][kh][(wn + n * 16 + l16) * 32 + qs]);
  };
  auto mma = [&](int mh) __attribute__((always_inline)) {
    __builtin_amdgcn_s_setprio(1);
#pragma unroll
    for (int i = 0; i < 4; ++i)
#pragma unroll
      for (int n = 0; n < 4; ++n)
        acc[mh * 4 + i][n] = mfma16(af[i], bfr[n], acc[mh * 4 + i][n]);
    __builtin_amdgcn_s_setprio(0);
  };

  const int NT    = K >> 6;               // 32 K-tiles (BK=64)
  const int ITERS = NT >> 1;              // 16 iters (2 K-tiles each)

  // prologue: 7 halves of tiles 0,1 in FIFO order matching the steady ledger.
  stB(0, 0, 0); stA(0, 0, 0); stB(0, 1, 0); stA(0, 1, 0);
  stB(1, 0, 1); stA(1, 0, 1); stB(1, 1, 1);

  for (int I = 0; I < ITERS; ++I) {
    const int o   = 2 * I + 1;
    const int te2 = (2 * I + 2 < NT) ? 2 * I + 2 : NT - 1;  // clamped tail
    const int to2 = (2 * I + 3 < NT) ? 2 * I + 3 : NT - 1;

    // p1: e kh0 mh0 | stage A[b1]kh1 <- o | wait
    WAIT_VM6();
    BARRIER();
    lda(0, 0, 0); ldb(0, 0);
    stA(1, 1, o);
    mma(0);
    // p2: e kh0 mh1 | stage B[b0]kh0 <- e+2
    BARRIER();
    lda(0, 0, 1);
    stB(0, 0, te2);
    mma(1);
    // p3: e kh1 mh0 | stage A[b0]kh0 <- e+2
    BARRIER();
    lda(0, 1, 0); ldb(0, 1);
    stA(0, 0, te2);
    mma(0);
    // p4: e kh1 mh1 | stage B[b0]kh1 <- e+2
    BARRIER();
    lda(0, 1, 1);
    stB(0, 1, te2);
    mma(1);
    // p5: o kh0 mh0 | stage A[b0]kh1 <- e+2 | wait
    WAIT_VM6();
    BARRIER();
    lda(1, 0, 0); ldb(1, 0);
    stA(0, 1, te2);
    mma(0);
    // p6: o kh0 mh1 | stage B[b1]kh0 <- o+2
    BARRIER();
    lda(1, 0, 1);
    stB(1, 0, to2);
    mma(1);
    // p7: o kh1 mh0 | stage A[b1]kh0 <- o+2
    BARRIER();
    lda(1, 1, 0); ldb(1, 1);
    stA(1, 0, to2);
    mma(0);
    // p8: o kh1 mh1 | stage B[b1]kh1 <- o+2
    BARRIER();
    lda(1, 1, 1);
    stB(1, 1, to2);
    mma(1);
  }

  // drain remaining lds-DMA before epilogue/endpgm (LDS may be reallocated).
  asm volatile("s_waitcnt vmcnt(0)" ::: "memory");

  // epilogue: C/D layout row = quad*4+v, col = l16 per 16x16 fragment
#pragma unroll
  for (int mt = 0; mt < 8; ++mt)
#pragma unroll
    for (int nt = 0; nt < 4; ++nt)
#pragma unroll
      for (int v = 0; v < 4; ++v) {
        int row = bm + wm + mt * 16 + quad * 4 + v;
        int col = bn + wn + nt * 16 + l16;
        if (vtout) {
          // row = b*S+s, col = h*128+d -> Vt[((b*16+h)*128+d)*S + s]
          size_t o = (size_t)(((row >> 11) * 16 + (col >> 7)) * 128 + (col & 127)) * S_ +
                     (row & 2047);
          C[o] = (TC)acc[mt][nt][v];
        } else {
          C[(size_t)row * DM_ + col] = (TC)acc[mt][nt][v];
        }
      }
}

// fused Q/K/V projection: 768 blocks; seg = bid>>8 picks weight + output.
__global__ __launch_bounds__(512, 2) void qkv_gemm(
    const bf16_t* __restrict__ xb, const bf16_t* __restrict__ wq,
    const bf16_t* __restrict__ wk, const bf16_t* __restrict__ wv,
    bf16_t* __restrict__ Qb, bf16_t* __restrict__ Kb, bf16_t* __restrict__ Vt) {
  __shared__ bf16_t Ab[2][2][8192];
  __shared__ bf16_t Bb[2][2][8192];
  const int seg  = (int)blockIdx.x >> 8;
  const int b256 = (int)blockIdx.x & 255;
  const bf16_t* W = (seg == 0) ? wq : (seg == 1) ? wk : wv;
  bf16_t* C       = (seg == 0) ? Qb : (seg == 1) ? Kb : Vt;
  gemm_body<bf16_t>(xb, W, C, seg == 2, b256, Ab, Bb);
}

// output projection: fp32 C.
__global__ __launch_bounds__(512, 2) void out_gemm(
    const bf16_t* __restrict__ Ob, const bf16_t* __restrict__ Wob,
    float* __restrict__ out) {
  __shared__ bf16_t Ab[2][2][8192];
  __shared__ bf16_t Bb[2][2][8192];
  gemm_body<float>(Ob, Wob, out, false, (int)blockIdx.x, Ab, Bb);
}

// ---------------------------------------------------------------------------
// Flash attention, dual-chain load-balanced version (measured 153.9 us r5):
//  * One workgroup owns TWO q-blocks {qa=31-p, qc=p}: constant 33 work-units.
//  * Both chains consume the SAME staged K/V tile (shared kf/vf ds_reads).
//  * K/V double-buffered, global_load_lds issued one tile ahead.
//  * XOR-swizzled LDS, inverse-swizzled global sources.
//  * DPP row_ror softmax reductions; Q direct global->reg; defer-max; setprio.
// LDS: Ks 32K + Vs 32K + Ps 16K = 80KB -> 2 blocks/CU.
// Q,K: [b*S+s][h*128+d] bf16.  VT: [(b*16+h)*128+d][s] bf16.  O like Q.
// ---------------------------------------------------------------------------
__global__ __launch_bounds__(256, 2) void attn_kernel(const bf16_t* __restrict__ Q,
                                                      const bf16_t* __restrict__ K,
                                                      const bf16_t* __restrict__ VT,
                                                      bf16_t* __restrict__ O,
                                                      const int* __restrict__ use_mask) {
  __shared__ bf16_t Ks[2 * 64 * 128];   // [buf][k][d], XOR-swizzled
  __shared__ bf16_t Vs[2 * 128 * 64];   // [buf][d][k], XOR-swizzled
  __shared__ bf16_t Ps[2 * 4 * 16 * 64];// [chain][wave][16][64], XOR-swizzled

  const int tid  = threadIdx.x;
  const int wave = tid >> 6;
  const int lane = tid & 63;
  const int quad = lane >> 4;
  const int l16  = lane & 15;

  const int lid  = (int)(blockIdx.y * gridDim.x + blockIdx.x);
  const int xcd  = lid & 7;
  const int t8   = lid >> 3;                 // 0..127
  const int bh   = xcd + ((t8 >> 4) << 3);   // 8 heads per XCD
  const int pair = t8 & 15;
  const int qa   = 31 - pair;                // heavy q-block (17..32 tiles)
  const int qc   = pair;                     // light q-block (1..16 tiles)
  const int b = bh >> 4, h = bh & 15;
  const int maskflag = *use_mask;

  const size_t qbaseA = ((size_t)b * S_ + (size_t)qa * 64) * DM_ + h * DK_;
  const size_t qbaseC = ((size_t)b * S_ + (size_t)qc * 64) * DM_ + h * DK_;

  int skO[4], svO[4];
#pragma unroll
  for (int p = 0; p < 4; ++p) {
    int rK = p * 16 + wave * 4 + quad;
    skO[p] = rK * DM_ + ((l16 ^ (rK & 7)) * 8);
    int dV = p * 32 + wave * 8 + (lane >> 3);
    svO[p] = dV * S_ + (((lane & 7) ^ (dV & 7)) * 8);
  }

  const bf16_t* Kbase = K + (size_t)b * S_ * DM_ + h * DK_;
  const bf16_t* Vbase = VT + (size_t)bh * DK_ * S_;

  auto stage_kv = [&](int j, int buf) __attribute__((always_inline)) {
    const bf16_t* kb = Kbase + (size_t)j * 64 * DM_;
    const bf16_t* vb = Vbase + (size_t)j * 64;
    bf16_t* kl = Ks + buf * 8192 + wave * 512;
    bf16_t* vl = Vs + buf * 8192 + wave * 512;
#pragma unroll
    for (int p = 0; p < 4; ++p) {
      async_copy16(kb + skO[p], kl + p * 2048);
      async_copy16(vb + svO[p], vl + p * 2048);
    }
  };

  bf16x8 qfA[4], qfC[4];
#pragma unroll
  for (int kk = 0; kk < 4; ++kk) {
    size_t ro = (size_t)(wave * 16 + l16) * DM_ + kk * 32 + quad * 8;
    qfA[kk] = *(const bf16x8*)(Q + qbaseA + ro);
    qfC[kk] = *(const bf16x8*)(Q + qbaseC + ro);
  }

  stage_kv(0, 0);

  f32x4 accA[8], accC[8];
#pragma unroll
  for (int i = 0; i < 8; ++i) {
    accA[i] = (f32x4){0.f, 0.f, 0.f, 0.f};
    accC[i] = (f32x4){0.f, 0.f, 0.f, 0.f};
  }
  float mA[4], lA[4], mC[4], lC[4];
#pragma unroll
  for (int v = 0; v < 4; ++v) {
    mA[v] = -INFINITY; lA[v] = 0.f;
    mC[v] = -INFINITY; lC[v] = 0.f;
  }

  bf16_t* PwA = Ps + wave * 1024;
  bf16_t* PwC = Ps + 4096 + wave * 1024;

  const float c1 = 0.08838834764831845f * 1.4426950408889634f;

  const int ntA = maskflag ? qa + 1 : (S_ / 64);
  const int ntC = maskflag ? qc + 1 : (S_ / 64);

  auto softmax_chain = [&](f32x4 (&s)[4], float (&mrow)[4], float (&lrow)[4],
                           f32x4 (&acc)[8], bf16_t* Pw, bool masked)
      __attribute__((always_inline)) {
#pragma unroll
    for (int v = 0; v < 4; ++v) {
      float x[4];
#pragma unroll
      for (int nt = 0; nt < 4; ++nt) {
        float y = s[nt][v] * c1;
        if (masked) {
          int kg = nt * 16 + l16;
          int qg = wave * 16 + quad * 4 + v;
          if (kg > qg) y = -INFINITY;
        }
        x[nt] = y;
      }
      float r = fmaxf(fmaxf(x[0], x[1]), fmaxf(x[2], x[3]));
      r = rowmax16(r);
      float m = mrow[v];
      if (r > m + 8.f) {
        float alpha = __builtin_amdgcn_exp2f(m - r);
        lrow[v] *= alpha;
#pragma unroll
        for (int dt = 0; dt < 8; ++dt) acc[dt][v] *= alpha;
        mrow[v] = r;
        m = r;
      }
      float rs = 0.f;
      int prow = quad * 4 + v;
#pragma unroll
      for (int nt = 0; nt < 4; ++nt) {
        float p = __builtin_amdgcn_exp2f(x[nt] - m);
        rs += p;
        Pw[prow * 64 + ((nt * 16 + l16) ^ ((prow & 7) << 3))] = (bf16_t)p;
      }
      lrow[v] += rowsum16(rs);
    }
  };

  auto body = [&](auto DOC, int cur, bool maskedA, bool maskedC)
      __attribute__((always_inline)) {
    constexpr bool doC = decltype(DOC)::v;
    const bf16_t* KsB = Ks + cur * 8192;
    const bf16_t* VsB = Vs + cur * 8192;

    f32x4 sA[4], sC[4];
#pragma unroll
    for (int nt = 0; nt < 4; ++nt) {
      sA[nt] = (f32x4){0.f, 0.f, 0.f, 0.f};
      sC[nt] = (f32x4){0.f, 0.f, 0.f, 0.f};
    }
    __builtin_amdgcn_s_setprio(1);
#pragma unroll
    for (int kk = 0; kk < 4; ++kk) {
#pragma unroll
      for (int nt = 0; nt < 4; ++nt) {
        bf16x8 kf = *(const bf16x8*)(KsB + (nt * 16 + l16) * 128 +
                                     ((kk * 32 + quad * 8) ^ ((l16 & 7) << 3)));
        sA[nt] = mfma16(qfA[kk], kf, sA[nt]);
        if constexpr (doC) sC[nt] = mfma16(qfC[kk], kf, sC[nt]);
      }
    }
    __builtin_amdgcn_s_setprio(0);

    softmax_chain(sA, mA, lA, accA, PwA, maskedA);
    if constexpr (doC) softmax_chain(sC, mC, lC, accC, PwC, maskedC);

    __builtin_amdgcn_s_setprio(1);
#pragma unroll
    for (int kk = 0; kk < 2; ++kk) {
      bf16x8 pfA = *(const bf16x8*)(PwA + l16 * 64 +
                                    ((kk * 32 + quad * 8) ^ ((l16 & 7) << 3)));
      bf16x8 pfC = {};
      if constexpr (doC)
        pfC = *(const bf16x8*)(PwC + l16 * 64 +
                               ((kk * 32 + quad * 8) ^ ((l16 & 7) << 3)));
#pragma unroll
      for (int dt = 0; dt < 8; ++dt) {
        bf16x8 vf = *(const bf16x8*)(VsB + (dt * 16 + l16) * 64 +
                                     ((kk * 32 + quad * 8) ^ ((l16 & 7) << 3)));
        accA[dt] = mfma16(pfA, vf, accA[dt]);
        if constexpr (doC) accC[dt] = mfma16(pfC, vf, accC[dt]);
      }
    }
    __builtin_amdgcn_s_setprio(0);
  };

  __syncthreads();

  for (int t = 0; t < ntA; ++t) {
    const int cur = t & 1;
    if (t + 1 < ntA) stage_kv(t + 1, cur ^ 1);
    const bool mAf = maskflag && (t == qa);
    if (t < ntC)
      body(ChainOn{},  cur, mAf, maskflag && (t == qc));
    else
      body(ChainOff{}, cur, mAf, false);
    __syncthreads();
  }

  auto epilogue = [&](f32x4 (&acc)[8], float (&lrow)[4], size_t qbase)
      __attribute__((always_inline)) {
    float rl[4];
#pragma unroll
    for (int v = 0; v < 4; ++v) rl[v] = __builtin_amdgcn_rcpf(lrow[v]);
#pragma unroll
    for (int dt = 0; dt < 8; ++dt)
#pragma unroll
      for (int v = 0; v < 4; ++v) {
        int qr = wave * 16 + quad * 4 + v;
        O[qbase + (size_t)qr * DM_ + dt * 16 + l16] = (bf16_t)(acc[dt][v] * rl[v]);
      }
  };
  epilogue(accA, lA, qbaseA);
  epilogue(accC, lC, qbaseC);
}

// ---------------------------------------------------------------------------
extern "C" void kernel_launch(void* const* d_in, const int* in_sizes, int n_in,
                              void* d_out, int out_size, void* d_ws, size_t ws_size,
                              hipStream_t stream) {
  const float* x  = (const float*)d_in[0];
  const float* Wq = (const float*)d_in[1];
  const float* Wk = (const float*)d_in[2];
  const float* Wv = (const float*)d_in[3];
  const float* Wo = (const float*)d_in[4];
  const int* use_mask = (const int*)d_in[5];
  float* out = (float*)d_out;

  const size_t TSZ = (size_t)BS_ * DM_;   // 16,777,216 elems (32 MiB bf16)
  const size_t WSZ = (size_t)DM_ * DM_;   //  4,194,304 elems ( 8 MiB bf16)
  bf16_t* Qb  = (bf16_t*)d_ws;            // R0
  bf16_t* Kb  = Qb + TSZ;                 // R1
  bf16_t* Vt  = Kb + TSZ;                 // R2: Vt, then Wo_bf16 after attention
  bf16_t* xb  = Vt + TSZ;                 // R3: x_bf16, then Ob after projections
  bf16_t* Ob  = xb;
  bf16_t* Wob = Vt;
  // weight bf16 staging inside d_out (64 MiB fp32; fully overwritten at the end)
  bf16_t* wq = (bf16_t*)d_out;
  bf16_t* wk = wq + WSZ;
  bf16_t* wv = wk + WSZ;

  cvt_bf16<<<(int)(TSZ / 8 / 256), 256, 0, stream>>>(x,  xb, (int)(TSZ / 8));
  cvt_bf16<<<(int)(WSZ / 8 / 256), 256, 0, stream>>>(Wq, wq, (int)(WSZ / 8));
  cvt_bf16<<<(int)(WSZ / 8 / 256), 256, 0, stream>>>(Wk, wk, (int)(WSZ / 8));
  cvt_bf16<<<(int)(WSZ / 8 / 256), 256, 0, stream>>>(Wv, wv, (int)(WSZ / 8));

  qkv_gemm<<<dim3(768), 512, 0, stream>>>(xb, wq, wk, wv, Qb, Kb, Vt);

  dim3 gA(16, 64);                   // 1024 balanced dual-q blocks
  attn_kernel<<<gA, 256, 0, stream>>>(Qb, Kb, Vt, Ob, use_mask);

  cvt_bf16<<<(int)(WSZ / 8 / 256), 256, 0, stream>>>(Wo, Wob, (int)(WSZ / 8));
  out_gemm<<<dim3(256), 512, 0, stream>>>(Ob, Wob, out);
}

// Round 10
// 576.263 us; speedup vs baseline: 1.1365x; 1.0433x over previous
//
#include <hip/hip_runtime.h>
#include <hip/hip_bf16.h>

typedef __bf16 bf16_t;
typedef __bf16 bf16x8 __attribute__((ext_vector_type(8)));
typedef float f32x4 __attribute__((ext_vector_type(4)));

#define B_  4
#define S_  2048
#define H_  16
#define DK_ 128
#define DM_ 2048
#define BS_ (B_ * S_)          // 8192 rows

static __device__ __forceinline__ f32x4 mfma16(bf16x8 a, bf16x8 b, f32x4 c) {
  return __builtin_amdgcn_mfma_f32_16x16x32_bf16(a, b, c, 0, 0, 0);
}

// async global->LDS 16B copy. lds base must be wave-uniform; HW scatters lane*16.
static __device__ __forceinline__ void async_copy16(const bf16_t* g, bf16_t* l) {
  __builtin_amdgcn_global_load_lds(
      (const __attribute__((address_space(1))) void*)g,
      (__attribute__((address_space(3))) void*)l, 16, 0, 0);
}

// raw workgroup barrier WITHOUT the vmcnt(0)/lgkmcnt(0) drain __syncthreads
// emits; "memory" clobber = compiler fence.
#define BARRIER() asm volatile("s_barrier" ::: "memory")
#define WAIT_VM6() asm volatile("s_waitcnt vmcnt(6)" ::: "memory")

// DPP row_ror (within 16-lane row) on f32 -- cross-lane reduce on the VALU pipe.
template <int CTRL>
static __device__ __forceinline__ float dpp_rorf(float x) {
  return __builtin_bit_cast(float,
      __builtin_amdgcn_update_dpp(0, __builtin_bit_cast(int, x), CTRL, 0xF, 0xF, true));
}
static __device__ __forceinline__ float rowmax16(float r) {
  r = fmaxf(r, dpp_rorf<0x121>(r));
  r = fmaxf(r, dpp_rorf<0x122>(r));
  r = fmaxf(r, dpp_rorf<0x124>(r));
  r = fmaxf(r, dpp_rorf<0x128>(r));
  return r;
}
static __device__ __forceinline__ float rowsum16(float r) {
  r += dpp_rorf<0x121>(r);
  r += dpp_rorf<0x122>(r);
  r += dpp_rorf<0x124>(r);
  r += dpp_rorf<0x128>(r);
  return r;
}

struct ChainOn  { static constexpr bool v = true;  };
struct ChainOff { static constexpr bool v = false; };

// ---------------------------------------------------------------------------
// fp32 -> bf16 elementwise convert (8 elems/thread)
// ---------------------------------------------------------------------------
__global__ __launch_bounds__(256) void cvt_bf16(const float* __restrict__ in,
                                                bf16_t* __restrict__ out, int n8) {
  int i = blockIdx.x * 256 + threadIdx.x;
  if (i < n8) {
    const float4* p = (const float4*)in + (size_t)i * 2;
    float4 f0 = p[0], f1 = p[1];
    bf16x8 r;
    r[0] = (bf16_t)f0.x; r[1] = (bf16_t)f0.y; r[2] = (bf16_t)f0.z; r[3] = (bf16_t)f0.w;
    r[4] = (bf16_t)f1.x; r[5] = (bf16_t)f1.y; r[6] = (bf16_t)f1.z; r[7] = (bf16_t)f1.w;
    ((bf16x8*)out)[i] = r;
  }
}

// ---------------------------------------------------------------------------
// GEMM body: C[M,N] = A[M,K] * B[N,K]^T, 256x256 tile, 8 waves (2Mx4N).
// r9 post-mortem: ds_reads issued AFTER the phase barrier with MFMA
// immediately dependent -> per-phase DS latency fully exposed (~860 cyc of
// the 1480-cyc phase; MFMA floor is ~620). This version = m201's 2-barrier
// phase: {ds_read frags | stage 1 half | BAR1 | 16 MFMA | [vmcnt(6) @p4,p8]
// | BAR2}. Reads issue pre-BAR1 -> latency hides under barrier skew + the
// co-resident wave's MFMA; BAR2 separates read-retirement from the next
// phase's overwriting stage (the reason 2 barriers are required).
//
// Ledger (iter I: K-tiles e=2I buf0, o=2I+1 buf1; 2 loads/stage, FIFO):
//  Stages: p1:A[1]kh1<-o  p2:B[0]kh0<-e+2 p3:A[0]kh0<-e+2 p4:B[0]kh1<-e+2
//          p5:A[0]kh1<-e+2 p6:B[1]kh0<-o+2 p7:A[1]kh0<-o+2 p8:B[1]kh1<-o+2
//  Reads:  p1:A0kh0/mh0+B0kh0 p2:A0kh0/mh1 p3:A0kh1/mh0+B0kh1 p4:A0kh1/mh1
//          p5:A1kh0/mh0+B1kh0 p6:A1kh0/mh1 p7:A1kh1/mh0+B1kh1 p8:A1kh1/mh1
//  Wait end-p8(I-1), vmcnt(6): outstanding {p6,p7,p8} -> drains through
//  I-1.p5 = every half read at I.p1-p4 (latest: A0kh1 @ I-1.p5). All waves
//  pass the wait before BAR2(p8); I.p1-p4 reads issue after it. OK.
//  Wait end-p4(I), vmcnt(6): outstanding {p2,p3,p4} -> drains through I.p1 =
//  every half read at I.p5-p8 (latest: A1kh1 @ I.p1). OK.
//  Shortest flight = 3 phases (>2K cyc) >> HBM ~900. Overwrite safety: each
//  stage's target half had its last ds_reads retire (lgkm before MFMA)
//  before BAR2 of the prior phase; stage issues after that BAR2 (checked
//  for all 8 entries). Prologue: 7 halves staged; vmcnt(6) drains exactly
//  the 4 halves p1-p4 need. Tail stages clamp to NT-1 (dead slots, uniform
//  ledger). Final vmcnt(0) before epilogue (LDS may be reallocated).
// Swizzle (refcheck'd r6-r9): chunk q of row r at physical q ^ s(r),
// s(r) = (r + (r>>2)) & 3; LDS dest linear for global_load_lds; SOURCE chunk
// inverse-swizzled; ds_read applies the XOR (lane-only for 16-aligned rows).
// vtout: write C per-head-transposed into Vt layout [(b*16+h)*128+d][s].
// ---------------------------------------------------------------------------
template <typename TC>
static __device__ __forceinline__ void gemm_body(
    const bf16_t* __restrict__ A, const bf16_t* __restrict__ B, TC* __restrict__ C,
    bool vtout, int b256, bf16_t (&Ab)[2][2][8192], bf16_t (&Bb)[2][2][8192]) {
  const int tid  = threadIdx.x;
  const int wave = tid >> 6;              // 0..7
  const int lane = tid & 63;
  const int quad = lane >> 4;
  const int l16  = lane & 15;
  const int wm   = (wave >> 2) * 128;     // wave's M half
  const int wn   = (wave & 3) * 64;       // wave's N quarter

  // XCD-bijective remap: 256 blocks; each xcd owns a contiguous 4x8 stripe.
  const int xcd = b256 & 7;
  const int idx = b256 >> 3;              // 0..31
  const int bm  = (xcd * 4 + (idx >> 3)) * 256;
  const int bn  = (idx & 7) * 256;
  const int K   = DM_;

  // staging: one half-tile (256 rows x 32 cols) = 2 instructions/thread.
  const int r0 = wave * 16 + (lane >> 2);
  const int r1 = r0 + 128;
  const int s0 = (r0 + (r0 >> 2)) & 3;
  const int s1 = (r1 + (r1 >> 2)) & 3;
  const size_t aO0 = (size_t)(bm + r0) * K + ((lane & 3) ^ s0) * 8;
  const size_t aO1 = (size_t)(bm + r1) * K + ((lane & 3) ^ s1) * 8;
  const size_t bO0 = (size_t)(bn + r0) * K + ((lane & 3) ^ s0) * 8;
  const size_t bO1 = (size_t)(bn + r1) * K + ((lane & 3) ^ s1) * 8;
  const int dst0 = wave * 512;            // wave-uniform LDS elem offsets
  const int dst1 = 4096 + wave * 512;

  auto stA = [&](int buf, int kh, int kt) __attribute__((always_inline)) {
    const size_t c = (size_t)kt * 64 + kh * 32;
    async_copy16(A + aO0 + c, &Ab[buf][kh][dst0]);
    async_copy16(A + aO1 + c, &Ab[buf][kh][dst1]);
  };
  auto stB = [&](int buf, int kh, int kt) __attribute__((always_inline)) {
    const size_t c = (size_t)kt * 64 + kh * 32;
    async_copy16(B + bO0 + c, &Bb[buf][kh][dst0]);
    async_copy16(B + bO1 + c, &Bb[buf][kh][dst1]);
  };

  // fragment-read swizzle (lane-only: row bases are 16-aligned)
  const int sw = (l16 + (l16 >> 2)) & 3;
  const int qs = (quad ^ sw) * 8;

  f32x4 acc[8][4];
#pragma unroll
  for (int i = 0; i < 8; ++i)
#pragma unroll
    for (int j = 0; j < 4; ++j) acc[i][j] = (f32x4){0.f, 0.f, 0.f, 0.f};

  bf16x8 af[4], bfr[4];

  auto lda = [&](int buf, int kh, int mh) __attribute__((always_inline)) {
#pragma unroll
    for (int i = 0; i < 4; ++i)
      af[i] = *(const bf16x8*)(&Ab[buf][kh][(wm + mh * 64 + i * 16 + l16) * 32 + qs]);
  };
  auto ldb = [&](int buf, int kh) __attribute__((always_inline)) {
#pragma unroll
    for (int n = 0; n < 4; ++n)
      bfr[n] = *(const bf16x8*)(&Bb[buf][kh][(wn + n * 16 + l16) * 32 + qs]);
  };
  auto mma = [&](int mh) __attribute__((always_inline)) {
    __builtin_amdgcn_s_setprio(1);
#pragma unroll
    for (int i = 0; i < 4; ++i)
#pragma unroll
      for (int n = 0; n < 4; ++n)
        acc[mh * 4 + i][n] = mfma16(af[i], bfr[n], acc[mh * 4 + i][n]);
    __builtin_amdgcn_s_setprio(0);
  };

  const int NT    = K >> 6;               // 32 K-tiles (BK=64)
  const int ITERS = NT >> 1;              // 16 iters (2 K-tiles each)

  // prologue: 7 halves of tiles 0,1 in ledger FIFO order; vmcnt(6) leaves
  // {B1kh0,A1kh0,B1kh1} in flight = drains the 4 halves p1-p4 read.
  stB(0, 0, 0); stA(0, 0, 0); stB(0, 1, 0); stA(0, 1, 0);
  stB(1, 0, 1); stA(1, 0, 1); stB(1, 1, 1);
  WAIT_VM6();
  BARRIER();

  for (int I = 0; I < ITERS; ++I) {
    const int o   = 2 * I + 1;
    const int te2 = (2 * I + 2 < NT) ? 2 * I + 2 : NT - 1;  // clamped tail
    const int to2 = (2 * I + 3 < NT) ? 2 * I + 3 : NT - 1;

    // p1: reads e kh0 (mh0 + B) | stage A[b1]kh1 <- o
    lda(0, 0, 0); ldb(0, 0);
    stA(1, 1, o);
    BARRIER();
    mma(0);
    BARRIER();
    // p2: reads e kh0 mh1 | stage B[b0]kh0 <- e+2
    lda(0, 0, 1);
    stB(0, 0, te2);
    BARRIER();
    mma(1);
    BARRIER();
    // p3: reads e kh1 (mh0 + B) | stage A[b0]kh0 <- e+2
    lda(0, 1, 0); ldb(0, 1);
    stA(0, 0, te2);
    BARRIER();
    mma(0);
    BARRIER();
    // p4: reads e kh1 mh1 | stage B[b0]kh1 <- e+2 | WAIT (covers p5-p8 reads)
    lda(0, 1, 1);
    stB(0, 1, te2);
    BARRIER();
    mma(1);
    WAIT_VM6();
    BARRIER();
    // p5: reads o kh0 (mh0 + B) | stage A[b0]kh1 <- e+2
    lda(1, 0, 0); ldb(1, 0);
    stA(0, 1, te2);
    BARRIER();
    mma(0);
    BARRIER();
    // p6: reads o kh0 mh1 | stage B[b1]kh0 <- o+2
    lda(1, 0, 1);
    stB(1, 0, to2);
    BARRIER();
    mma(1);
    BARRIER();
    // p7: reads o kh1 (mh0 + B) | stage A[b1]kh0 <- o+2
    lda(1, 1, 0); ldb(1, 1);
    stA(1, 0, to2);
    BARRIER();
    mma(0);
    BARRIER();
    // p8: reads o kh1 mh1 | stage B[b1]kh1 <- o+2 | WAIT (covers next p1-p4)
    lda(1, 1, 1);
    stB(1, 1, to2);
    BARRIER();
    mma(1);
    WAIT_VM6();
    BARRIER();
  }

  // drain remaining lds-DMA before epilogue/endpgm (LDS may be reallocated).
  asm volatile("s_waitcnt vmcnt(0)" ::: "memory");

  // epilogue: C/D layout row = quad*4+v, col = l16 per 16x16 fragment
#pragma unroll
  for (int mt = 0; mt < 8; ++mt)
#pragma unroll
    for (int nt = 0; nt < 4; ++nt)
#pragma unroll
      for (int v = 0; v < 4; ++v) {
        int row = bm + wm + mt * 16 + quad * 4 + v;
        int col = bn + wn + nt * 16 + l16;
        if (vtout) {
          // row = b*S+s, col = h*128+d -> Vt[((b*16+h)*128+d)*S + s]
          size_t o = (size_t)(((row >> 11) * 16 + (col >> 7)) * 128 + (col & 127)) * S_ +
                     (row & 2047);
          C[o] = (TC)acc[mt][nt][v];
        } else {
          C[(size_t)row * DM_ + col] = (TC)acc[mt][nt][v];
        }
      }
}

// fused Q/K/V projection: 768 blocks; seg = bid>>8 picks weight + output.
__global__ __launch_bounds__(512, 2) void qkv_gemm(
    const bf16_t* __restrict__ xb, const bf16_t* __restrict__ wq,
    const bf16_t* __restrict__ wk, const bf16_t* __restrict__ wv,
    bf16_t* __restrict__ Qb, bf16_t* __restrict__ Kb, bf16_t* __restrict__ Vt) {
  __shared__ bf16_t Ab[2][2][8192];
  __shared__ bf16_t Bb[2][2][8192];
  const int seg  = (int)blockIdx.x >> 8;
  const int b256 = (int)blockIdx.x & 255;
  const bf16_t* W = (seg == 0) ? wq : (seg == 1) ? wk : wv;
  bf16_t* C       = (seg == 0) ? Qb : (seg == 1) ? Kb : Vt;
  gemm_body<bf16_t>(xb, W, C, seg == 2, b256, Ab, Bb);
}

// output projection: fp32 C.
__global__ __launch_bounds__(512, 2) void out_gemm(
    const bf16_t* __restrict__ Ob, const bf16_t* __restrict__ Wob,
    float* __restrict__ out) {
  __shared__ bf16_t Ab[2][2][8192];
  __shared__ bf16_t Bb[2][2][8192];
  gemm_body<float>(Ob, Wob, out, false, (int)blockIdx.x, Ab, Bb);
}

// ---------------------------------------------------------------------------
// Flash attention, dual-chain load-balanced version (measured 153.9 us r5):
//  * One workgroup owns TWO q-blocks {qa=31-p, qc=p}: constant 33 work-units.
//  * Both chains consume the SAME staged K/V tile (shared kf/vf ds_reads).
//  * K/V double-buffered, global_load_lds issued one tile ahead.
//  * XOR-swizzled LDS, inverse-swizzled global sources.
//  * DPP row_ror softmax reductions; Q direct global->reg; defer-max; setprio.
// LDS: Ks 32K + Vs 32K + Ps 16K = 80KB -> 2 blocks/CU.
// Q,K: [b*S+s][h*128+d] bf16.  VT: [(b*16+h)*128+d][s] bf16.  O like Q.
// ---------------------------------------------------------------------------
__global__ __launch_bounds__(256, 2) void attn_kernel(const bf16_t* __restrict__ Q,
                                                      const bf16_t* __restrict__ K,
                                                      const bf16_t* __restrict__ VT,
                                                      bf16_t* __restrict__ O,
                                                      const int* __restrict__ use_mask) {
  __shared__ bf16_t Ks[2 * 64 * 128];   // [buf][k][d], XOR-swizzled
  __shared__ bf16_t Vs[2 * 128 * 64];   // [buf][d][k], XOR-swizzled
  __shared__ bf16_t Ps[2 * 4 * 16 * 64];// [chain][wave][16][64], XOR-swizzled

  const int tid  = threadIdx.x;
  const int wave = tid >> 6;
  const int lane = tid & 63;
  const int quad = lane >> 4;
  const int l16  = lane & 15;

  const int lid  = (int)(blockIdx.y * gridDim.x + blockIdx.x);
  const int xcd  = lid & 7;
  const int t8   = lid >> 3;                 // 0..127
  const int bh   = xcd + ((t8 >> 4) << 3);   // 8 heads per XCD
  const int pair = t8 & 15;
  const int qa   = 31 - pair;                // heavy q-block (17..32 tiles)
  const int qc   = pair;                     // light q-block (1..16 tiles)
  const int b = bh >> 4, h = bh & 15;
  const int maskflag = *use_mask;

  const size_t qbaseA = ((size_t)b * S_ + (size_t)qa * 64) * DM_ + h * DK_;
  const size_t qbaseC = ((size_t)b * S_ + (size_t)qc * 64) * DM_ + h * DK_;

  int skO[4], svO[4];
#pragma unroll
  for (int p = 0; p < 4; ++p) {
    int rK = p * 16 + wave * 4 + quad;
    skO[p] = rK * DM_ + ((l16 ^ (rK & 7)) * 8);
    int dV = p * 32 + wave * 8 + (lane >> 3);
    svO[p] = dV * S_ + (((lane & 7) ^ (dV & 7)) * 8);
  }

  const bf16_t* Kbase = K + (size_t)b * S_ * DM_ + h * DK_;
  const bf16_t* Vbase = VT + (size_t)bh * DK_ * S_;

  auto stage_kv = [&](int j, int buf) __attribute__((always_inline)) {
    const bf16_t* kb = Kbase + (size_t)j * 64 * DM_;
    const bf16_t* vb = Vbase + (size_t)j * 64;
    bf16_t* kl = Ks + buf * 8192 + wave * 512;
    bf16_t* vl = Vs + buf * 8192 + wave * 512;
#pragma unroll
    for (int p = 0; p < 4; ++p) {
      async_copy16(kb + skO[p], kl + p * 2048);
      async_copy16(vb + svO[p], vl + p * 2048);
    }
  };

  bf16x8 qfA[4], qfC[4];
#pragma unroll
  for (int kk = 0; kk < 4; ++kk) {
    size_t ro = (size_t)(wave * 16 + l16) * DM_ + kk * 32 + quad * 8;
    qfA[kk] = *(const bf16x8*)(Q + qbaseA + ro);
    qfC[kk] = *(const bf16x8*)(Q + qbaseC + ro);
  }

  stage_kv(0, 0);

  f32x4 accA[8], accC[8];
#pragma unroll
  for (int i = 0; i < 8; ++i) {
    accA[i] = (f32x4){0.f, 0.f, 0.f, 0.f};
    accC[i] = (f32x4){0.f, 0.f, 0.f, 0.f};
  }
  float mA[4], lA[4], mC[4], lC[4];
#pragma unroll
  for (int v = 0; v < 4; ++v) {
    mA[v] = -INFINITY; lA[v] = 0.f;
    mC[v] = -INFINITY; lC[v] = 0.f;
  }

  bf16_t* PwA = Ps + wave * 1024;
  bf16_t* PwC = Ps + 4096 + wave * 1024;

  const float c1 = 0.08838834764831845f * 1.4426950408889634f;

  const int ntA = maskflag ? qa + 1 : (S_ / 64);
  const int ntC = maskflag ? qc + 1 : (S_ / 64);

  auto softmax_chain = [&](f32x4 (&s)[4], float (&mrow)[4], float (&lrow)[4],
                           f32x4 (&acc)[8], bf16_t* Pw, bool masked)
      __attribute__((always_inline)) {
#pragma unroll
    for (int v = 0; v < 4; ++v) {
      float x[4];
#pragma unroll
      for (int nt = 0; nt < 4; ++nt) {
        float y = s[nt][v] * c1;
        if (masked) {
          int kg = nt * 16 + l16;
          int qg = wave * 16 + quad * 4 + v;
          if (kg > qg) y = -INFINITY;
        }
        x[nt] = y;
      }
      float r = fmaxf(fmaxf(x[0], x[1]), fmaxf(x[2], x[3]));
      r = rowmax16(r);
      float m = mrow[v];
      if (r > m + 8.f) {
        float alpha = __builtin_amdgcn_exp2f(m - r);
        lrow[v] *= alpha;
#pragma unroll
        for (int dt = 0; dt < 8; ++dt) acc[dt][v] *= alpha;
        mrow[v] = r;
        m = r;
      }
      float rs = 0.f;
      int prow = quad * 4 + v;
#pragma unroll
      for (int nt = 0; nt < 4; ++nt) {
        float p = __builtin_amdgcn_exp2f(x[nt] - m);
        rs += p;
        Pw[prow * 64 + ((nt * 16 + l16) ^ ((prow & 7) << 3))] = (bf16_t)p;
      }
      lrow[v] += rowsum16(rs);
    }
  };

  auto body = [&](auto DOC, int cur, bool maskedA, bool maskedC)
      __attribute__((always_inline)) {
    constexpr bool doC = decltype(DOC)::v;
    const bf16_t* KsB = Ks + cur * 8192;
    const bf16_t* VsB = Vs + cur * 8192;

    f32x4 sA[4], sC[4];
#pragma unroll
    for (int nt = 0; nt < 4; ++nt) {
      sA[nt] = (f32x4){0.f, 0.f, 0.f, 0.f};
      sC[nt] = (f32x4){0.f, 0.f, 0.f, 0.f};
    }
    __builtin_amdgcn_s_setprio(1);
#pragma unroll
    for (int kk = 0; kk < 4; ++kk) {
#pragma unroll
      for (int nt = 0; nt < 4; ++nt) {
        bf16x8 kf = *(const bf16x8*)(KsB + (nt * 16 + l16) * 128 +
                                     ((kk * 32 + quad * 8) ^ ((l16 & 7) << 3)));
        sA[nt] = mfma16(qfA[kk], kf, sA[nt]);
        if constexpr (doC) sC[nt] = mfma16(qfC[kk], kf, sC[nt]);
      }
    }
    __builtin_amdgcn_s_setprio(0);

    softmax_chain(sA, mA, lA, accA, PwA, maskedA);
    if constexpr (doC) softmax_chain(sC, mC, lC, accC, PwC, maskedC);

    __builtin_amdgcn_s_setprio(1);
#pragma unroll
    for (int kk = 0; kk < 2; ++kk) {
      bf16x8 pfA = *(const bf16x8*)(PwA + l16 * 64 +
                                    ((kk * 32 + quad * 8) ^ ((l16 & 7) << 3)));
      bf16x8 pfC = {};
      if constexpr (doC)
        pfC = *(const bf16x8*)(PwC + l16 * 64 +
                               ((kk * 32 + quad * 8) ^ ((l16 & 7) << 3)));
#pragma unroll
      for (int dt = 0; dt < 8; ++dt) {
        bf16x8 vf = *(const bf16x8*)(VsB + (dt * 16 + l16) * 64 +
                                     ((kk * 32 + quad * 8) ^ ((l16 & 7) << 3)));
        accA[dt] = mfma16(pfA, vf, accA[dt]);
        if constexpr (doC) accC[dt] = mfma16(pfC, vf, accC[dt]);
      }
    }
    __builtin_amdgcn_s_setprio(0);
  };

  __syncthreads();

  for (int t = 0; t < ntA; ++t) {
    const int cur = t & 1;
    if (t + 1 < ntA) stage_kv(t + 1, cur ^ 1);
    const bool mAf = maskflag && (t == qa);
    if (t < ntC)
      body(ChainOn{},  cur, mAf, maskflag && (t == qc));
    else
      body(ChainOff{}, cur, mAf, false);
    __syncthreads();
  }

  auto epilogue = [&](f32x4 (&acc)[8], float (&lrow)[4], size_t qbase)
      __attribute__((always_inline)) {
    float rl[4];
#pragma unroll
    for (int v = 0; v < 4; ++v) rl[v] = __builtin_amdgcn_rcpf(lrow[v]);
#pragma unroll
    for (int dt = 0; dt < 8; ++dt)
#pragma unroll
      for (int v = 0; v < 4; ++v) {
        int qr = wave * 16 + quad * 4 + v;
        O[qbase + (size_t)qr * DM_ + dt * 16 + l16] = (bf16_t)(acc[dt][v] * rl[v]);
      }
  };
  epilogue(accA, lA, qbaseA);
  epilogue(accC, lC, qbaseC);
}

// ---------------------------------------------------------------------------
extern "C" void kernel_launch(void* const* d_in, const int* in_sizes, int n_in,
                              void* d_out, int out_size, void* d_ws, size_t ws_size,
                              hipStream_t stream) {
  const float* x  = (const float*)d_in[0];
  const float* Wq = (const float*)d_in[1];
  const float* Wk = (const float*)d_in[2];
  const float* Wv = (const float*)d_in[3];
  const float* Wo = (const float*)d_in[4];
  const int* use_mask = (const int*)d_in[5];
  float* out = (float*)d_out;

  const size_t TSZ = (size_t)BS_ * DM_;   // 16,777,216 elems (32 MiB bf16)
  const size_t WSZ = (size_t)DM_ * DM_;   //  4,194,304 elems ( 8 MiB bf16)
  bf16_t* Qb  = (bf16_t*)d_ws;            // R0
  bf16_t* Kb  = Qb + TSZ;                 // R1
  bf16_t* Vt  = Kb + TSZ;                 // R2: Vt, then Wo_bf16 after attention
  bf16_t* xb  = Vt + TSZ;                 // R3: x_bf16, then Ob after projections
  bf16_t* Ob  = xb;
  bf16_t* Wob = Vt;
  // weight bf16 staging inside d_out (64 MiB fp32; fully overwritten at the end)
  bf16_t* wq = (bf16_t*)d_out;
  bf16_t* wk = wq + WSZ;
  bf16_t* wv = wk + WSZ;

  cvt_bf16<<<(int)(TSZ / 8 / 256), 256, 0, stream>>>(x,  xb, (int)(TSZ / 8));
  cvt_bf16<<<(int)(WSZ / 8 / 256), 256, 0, stream>>>(Wq, wq, (int)(WSZ / 8));
  cvt_bf16<<<(int)(WSZ / 8 / 256), 256, 0, stream>>>(Wk, wk, (int)(WSZ / 8));
  cvt_bf16<<<(int)(WSZ / 8 / 256), 256, 0, stream>>>(Wv, wv, (int)(WSZ / 8));

  qkv_gemm<<<dim3(768), 512, 0, stream>>>(xb, wq, wk, wv, Qb, Kb, Vt);

  dim3 gA(16, 64);                   // 1024 balanced dual-q blocks
  attn_kernel<<<gA, 256, 0, stream>>>(Qb, Kb, Vt, Ob, use_mask);

  cvt_bf16<<<(int)(WSZ / 8 / 256), 256, 0, stream>>>(Wo, Wob, (int)(WSZ / 8));
  out_gemm<<<dim3(256), 512, 0, stream>>>(Ob, Wob, out);
}